// Round 9
// baseline (609.513 us; speedup 1.0000x reference)
//
#include <hip/hip_runtime.h>
#include <hip/hip_cooperative_groups.h>

namespace cg = cooperative_groups;

typedef unsigned short u16;
typedef unsigned int u32;
typedef unsigned long long u64;
typedef float f32x4 __attribute__((ext_vector_type(4)));
typedef float f32x16 __attribute__((ext_vector_type(16)));
typedef __bf16 bf16x4 __attribute__((ext_vector_type(4)));
typedef __bf16 bf16x8 __attribute__((ext_vector_type(8)));
typedef u16 u16x8 __attribute__((ext_vector_type(8)));
typedef u32 u32x4 __attribute__((ext_vector_type(4)));

#define QSCALE 0.18033688011112042f   /* 0.125 * log2(e) */

// ---------- helpers ----------
__device__ __forceinline__ u16 f2bf(float f) {
  unsigned int u = __float_as_uint(f);
  u += 0x7fffu + ((u >> 16) & 1u);   // round-to-nearest-even
  return (u16)(u >> 16);
}

// async global->LDS, 16B per lane; HW dest = readfirstlane(l) + lane*16.
__device__ __forceinline__ void async16(const void* g, void* l) {
  __builtin_amdgcn_global_load_lds(
      (__attribute__((address_space(1))) void*)g,
      (__attribute__((address_space(3))) void*)l,
      16, 0, 0);
}

__device__ __forceinline__ f32x4 mfma16(bf16x8 a, bf16x8 b, f32x4 c) {
  return __builtin_amdgcn_mfma_f32_16x16x32_bf16(a, b, c, 0, 0, 0);
}

__device__ __forceinline__ f32x16 mfma32(bf16x8 a, bf16x8 b, f32x16 c) {
  return __builtin_amdgcn_mfma_f32_32x32x16_bf16(a, b, c, 0, 0, 0);
}

// pack two f32 -> dword of 2 bf16 (RNE)
__device__ __forceinline__ u32 cvtpk(float lo, float hi) {
  u32 r;
  asm("v_cvt_pk_bf16_f32 %0, %1, %2" : "=v"(r) : "v"(lo), "v"(hi));
  return r;
}

// a' = {a.lo32lanes, b.lo32lanes}; b' = {a.hi32lanes, b.hi32lanes}
__device__ __forceinline__ void pswap(u32& a, u32& b) {
  asm("v_permlane32_swap_b32 %0, %1" : "+v"(a), "+v"(b));
}

// ---------- mega-kernel arguments ----------
struct MegaArgs {
  const float* csrc[7];   // q,k,v,Wq,Wk,Wv,Wo (f32)
  u16* cdst[7];           // bf16 versions
  const int* mask;
  u64* pm;
  const float *bq, *bk, *bv, *bo;
  u16 *qp, *kp, *vt, *joint;
  float* out;
};

// ---------- GEMM tile body, 512 threads / 8 waves, 128x128 tile ----------
// mode 0: out (B,H,S,Dh)   mode 1: out (B,H,Dh,S) (operands pre-swapped,
// bias by row)   mode 2: MxN f32
__device__ __forceinline__ void gemm_tile(const u16* __restrict__ A,
                                          const u16* __restrict__ W,
                                          const float* __restrict__ bias,
                                          void* __restrict__ outraw, int mode,
                                          float oscale, int m0, int n0,
                                          char* lds) {
  u16* lA = (u16*)lds;            // [128][32]
  u16* lB = (u16*)(lds + 8192);   // [128][32]
  const int tid = threadIdx.x;
  const int lane = tid & 63, wv = tid >> 6;     // 8 waves
  const int wm = wv >> 1, wn = wv & 1;          // 4 x 2 wave grid
  const int l15 = lane & 15, quad = lane >> 4;
  const int srow = tid >> 2;                    // 0..127
  const int scol = (tid & 3) * 8;               // 0..24

  f32x4 acc[2][4] = {};

  for (int k0 = 0; k0 < 1024; k0 += 32) {
    async16(A + (size_t)(m0 + srow) * 1024 + k0 + scol, lds + tid * 16);
    async16(W + (size_t)(n0 + srow) * 1024 + k0 + scol, lds + 8192 + tid * 16);
    __syncthreads();
    bf16x8 af[2], bfr[4];
#pragma unroll
    for (int i = 0; i < 2; ++i)
      af[i] = *(const bf16x8*)(lA + (wm * 32 + i * 16 + l15) * 32 + quad * 8);
#pragma unroll
    for (int j = 0; j < 4; ++j)
      bfr[j] = *(const bf16x8*)(lB + (wn * 64 + j * 16 + l15) * 32 + quad * 8);
#pragma unroll
    for (int i = 0; i < 2; ++i)
#pragma unroll
      for (int j = 0; j < 4; ++j)
        acc[i][j] = mfma16(af[i], bfr[j], acc[i][j]);
    __syncthreads();
  }

#pragma unroll
  for (int i = 0; i < 2; ++i) {
    int mbase = m0 + wm * 32 + i * 16 + quad * 4;
#pragma unroll
    for (int j = 0; j < 4; ++j) {
      int n = n0 + wn * 64 + j * 16 + l15;
      float bv = bias[n];   // modes 0/2: bias by column
#pragma unroll
      for (int r = 0; r < 4; ++r) {
        int m = mbase + r;
        if (mode == 0) {
          float val = (acc[i][j][r] + bv) * oscale;
          int b = m >> 11, s = m & 2047, h = n >> 6, dh = n & 63;
          ((u16*)outraw)[((((size_t)b * 16 + h) * 2048 + s) << 6) + dh] = f2bf(val);
        } else if (mode == 1) {
          // swapped gemm: m = feature row, n = b*2048+s; bias by ROW
          float val = acc[i][j][r] + bias[m];
          int h = m >> 6, dh = m & 63, b = n >> 11, s = n & 2047;
          ((u16*)outraw)[((((size_t)b * 16 + h) * 64 + dh) << 11) + s] = f2bf(val);
        } else {
          float val = acc[i][j][r] + bv;
          ((float*)outraw)[(size_t)m * 1024 + n] = val;
        }
      }
    }
  }
}

// ---------- the single cooperative kernel ----------
// Phase A: f32->bf16 cvt (7 tensors) + mask pack       (grid-stride)
// Phase B: QKV projection GEMMs (768 tile jobs)
// Phase C: flash attention (512 jobs; unchanged R6 body, 58.9us standalone)
// Phase D: output GEMM (256 tile jobs)
__global__ __launch_bounds__(512, 2) void mega_kernel(MegaArgs a) {
  alignas(16) __shared__ char smem[32768];
  cg::grid_group grid = cg::this_grid();
  const int G = gridDim.x;
  const int tid = threadIdx.x;

  // ================= Phase A: cvt + pack =================
  {
    const int gtid = blockIdx.x * 512 + tid;
    const int gstr = G * 512;
    for (int i = gtid; i < 2097152; i += gstr) {
      int z, off;
      if (i < 1572864) { z = i >> 19; off = (i & 524287) * 8; }
      else { int j = i - 1572864; z = 3 + (j >> 17); off = (j & 131071) * 8; }
      const float* s = a.csrc[z] + off;
      f32x4 x0 = *(const f32x4*)s;
      f32x4 x1 = *(const f32x4*)(s + 4);
      u16x8 pk;
      pk[0]=f2bf(x0[0]); pk[1]=f2bf(x0[1]); pk[2]=f2bf(x0[2]); pk[3]=f2bf(x0[3]);
      pk[4]=f2bf(x1[0]); pk[5]=f2bf(x1[1]); pk[6]=f2bf(x1[2]); pk[7]=f2bf(x1[3]);
      *(u16x8*)(a.cdst[z] + off) = pk;
    }
    for (int i = gtid; i < 131072; i += gstr) {
      const int4* src = (const int4*)(a.mask + (size_t)i * 64);
      u64 bits = 0ull;
#pragma unroll
      for (int j = 0; j < 16; ++j) {
        int4 v = src[j];
        if (v.x) bits |= 1ull << (4 * j + 0);
        if (v.y) bits |= 1ull << (4 * j + 1);
        if (v.z) bits |= 1ull << (4 * j + 2);
        if (v.w) bits |= 1ull << (4 * j + 3);
      }
      a.pm[i] = bits;
    }
  }
  __threadfence();
  grid.sync();

  // ================= Phase B: QKV GEMMs (768 jobs) =================
  for (int job = blockIdx.x; job < 768; job += G) {
    int z = job >> 8, t = job & 255;
    int my = (t >> 3) * 128, nx = (t & 7) * 128;
    if (z == 0)
      gemm_tile(a.cdst[0], a.cdst[3], a.bq, a.qp, 0, QSCALE, my, nx, smem);
    else if (z == 1)
      gemm_tile(a.cdst[1], a.cdst[4], a.bk, a.kp, 0, 1.0f, my, nx, smem);
    else
      // V projection computed transposed (A<->W swapped) -> coalesced store
      gemm_tile(a.cdst[5], a.cdst[2], a.bv, a.vt, 1, 1.0f, nx, my, smem);
  }
  __threadfence();
  grid.sync();

  // ================= Phase C: flash attention (512 jobs) =================
  for (int bid = blockIdx.x; bid < 512; bid += G) {
    __syncthreads();   // protect smem reuse across jobs / phases
    const int lane = tid & 63, wv = tid >> 6;
    const int l31 = lane & 31, hi = lane >> 5, l7 = lane & 7;
    const int qg = wv >> 1, kh = wv & 1;    // q-group (0..3), kv-half

    // XCD-bijective decode: xcd = bid&7 = grp>>2 (4 heads per XCD)
    const int grp = ((bid & 7) << 2) | ((bid >> 3) & 3);   // 0..31 = (b,h)
    const int q0 = (bid >> 5) * 128;
    const int hd = grp & 15, b = grp >> 4;

    const size_t head_off = ((size_t)b * 16 + hd) * 2048 * 64;
    const u16* Qh = a.qp + head_off;   // [2048][64]  (pre-scaled)
    const u16* Kh = a.kp + head_off;   // [2048][64]
    const u16* Vh = a.vt + head_off;   // [64][2048]  (dh-major)
    const int qr = q0 + qg * 32 + l31;                  // this lane's q row
    const u32* pmq32 = (const u32*)(a.pm + ((size_t)b * 2048 + qr) * 32) + kh;

    // Q fragments: B-operand per dh-subtile d: lane holds Q[qr][d*16+hi*8+j]
    bf16x8 qf[4];
    {
      const u16* qrow = Qh + (size_t)qr * 64 + hi * 8;
#pragma unroll
      for (int d = 0; d < 4; ++d) qf[d] = *(const bf16x8*)(qrow + d * 16);
    }

    // staging: 512 slots of 16B per tile, ONE K-slot + ONE V-slot per thread.
    const int sd = tid;
    const int kr = sd >> 3, ks = ((sd & 7) ^ (kr & 7)) * 8;
    const u16* kg = Kh + (size_t)kr * 64 + ks;
    const u16* vg = Vh + (size_t)kr * 2048 + ks;

    f32x16 O[2] = {};              // O^T: dh=g*32+(r&3)+8*(r>>2)+4*hi, q=l31
    f32x4 lacc = {};               // 4-chain l partials (kv-half only)
    const f32x16 fz16 = {};

    // prologue: stage tile 0
    async16(kg, smem + sd * 16);
    async16(vg, smem + 16384 + sd * 16);

    for (int kt = 0; kt < 32; ++kt) {
      __syncthreads();

      // prefetch next tile
      if (kt != 31) {
        const size_t kadv = (size_t)(kt + 1) * 4096;   // 64 rows x 64 elems
        const int vadv = (kt + 1) * 64;                // +64 kv columns
        char* kd = smem + (((kt + 1) & 1) << 13);
        char* vd = smem + 16384 + (((kt + 1) & 1) << 13);
        async16(kg + kadv, kd + sd * 16);
        async16(vg + vadv, vd + sd * 16);
      }

      u32 wh = pmq32[2 * kt];      // mask bits for this wave's kv half
      const char* kc = smem + ((kt & 1) << 13);
      const char* vc = smem + 16384 + ((kt & 1) << 13);

      // ---- K fragments: A-operand, lane = K[kh*32+l31][d*16+hi*8+j] ----
      bf16x8 kf[4];
#pragma unroll
      for (int d = 0; d < 4; ++d)
        kf[d] = *(const bf16x8*)(kc + (kh * 32 + l31) * 128 +
                                 (((2 * d + hi) ^ l7) << 4));

      // ---- S^T (this wave's 32x32 kv-half), chained over dh ----
      f32x16 S;
      {
        __builtin_amdgcn_s_setprio(1);
        f32x16 s = mfma32(kf[0], qf[0], fz16);
        s = mfma32(kf[1], qf[1], s);
        s = mfma32(kf[2], qf[2], s);
        S = mfma32(kf[3], qf[3], s);
        __builtin_amdgcn_s_setprio(0);
      }

      // ---- V fragments: A-operand, lane = V^T[g*32+l31][vks*16+hi*8+j] ----
      bf16x8 vf[2][2];
#pragma unroll
      for (int g = 0; g < 2; ++g)
#pragma unroll
        for (int t = 0; t < 2; ++t) {
          int vks = kh * 2 + t;
          vf[g][t] = *(const bf16x8*)(vc + (g * 32 + l31) * 128 +
                                      (((2 * vks + hi) ^ l7) << 4));
        }

      // ---- masked exp2 + l accumulation (kv' = (r&3)+8*(r>>2)+4*hi) ----
      {
        const int hi4 = hi * 4;
#pragma unroll
        for (int rq = 0; rq < 4; ++rq) {
          u32 nib = wh >> (rq * 8 + hi4);
#pragma unroll
          for (int r4 = 0; r4 < 4; ++r4) {
            int i = rq * 4 + r4;
            float pe = __builtin_amdgcn_exp2f(S[i]);
            S[i] = ((nib >> r4) & 1u) ? pe : 0.f;
          }
          f32x4 sv = {S[rq * 4 + 0], S[rq * 4 + 1], S[rq * 4 + 2], S[rq * 4 + 3]};
          lacc += sv;
        }
      }

      // ---- P^T -> PV B-operand, in-register (cvt_pk + permlane, T12) ----
      bf16x8 pf[2];
#pragma unroll
      for (int t = 0; t < 2; ++t) {
        int ra = t * 8;
        u32 w0a = cvtpk(S[ra + 0], S[ra + 1]);
        u32 w1a = cvtpk(S[ra + 2], S[ra + 3]);
        u32 w0b = cvtpk(S[ra + 4], S[ra + 5]);
        u32 w1b = cvtpk(S[ra + 6], S[ra + 7]);
        pswap(w0a, w0b);   // dword0 / dword2
        pswap(w1a, w1b);   // dword1 / dword3
        u32x4 tt = {w0a, w1a, w0b, w1b};
        pf[t] = __builtin_bit_cast(bf16x8, tt);
      }

      // ---- O^T += V^T . P^T (this kv-half's contribution) ----
      __builtin_amdgcn_s_setprio(1);
#pragma unroll
      for (int g = 0; g < 2; ++g) {
        f32x16 o = O[g];
        o = mfma32(vf[g][0], pf[0], o);
        O[g] = mfma32(vf[g][1], pf[1], o);
      }
      __builtin_amdgcn_s_setprio(0);
    }

    // ---- epilogue: cross-wave (kv-half) reduction via 2-round exchange ----
    float lp = (lacc[0] + lacc[1]) + (lacc[2] + lacc[3]);
    lp += __shfl_xor(lp, 32, 64);  // hi/lo lanes hold complementary kv rows
    __syncthreads();               // all K/V tile reads done; smem reusable
    float* exch = (float*)smem;    // [4][64][17] floats, 17.4 KB
    float* e = exch + (qg * 64 + lane) * 17;
    if (kh == 1) {
#pragma unroll
      for (int i = 0; i < 16; ++i) e[i] = O[0][i];
      e[16] = lp;
    }
    __syncthreads();
    if (kh == 0) {
#pragma unroll
      for (int i = 0; i < 16; ++i) O[0][i] += e[i];
      lp += e[16];
    }
    __syncthreads();
    if (kh == 1) {
#pragma unroll
      for (int i = 0; i < 16; ++i) e[i] = O[1][i];
    }
    __syncthreads();
    if (kh == 0) {
#pragma unroll
      for (int i = 0; i < 16; ++i) O[1][i] += e[i];
      float inv = 1.0f / lp;
      size_t row_off = ((size_t)b * 2048 + qr) * 1024 + hd * 64;
#pragma unroll
      for (int g = 0; g < 2; ++g)
#pragma unroll
        for (int rq = 0; rq < 4; ++rq) {
          f32x4 ov = {O[g][rq * 4 + 0] * inv, O[g][rq * 4 + 1] * inv,
                      O[g][rq * 4 + 2] * inv, O[g][rq * 4 + 3] * inv};
          bf16x4 obv = __builtin_convertvector(ov, bf16x4);
          *(u64*)(a.joint + row_off + g * 32 + rq * 8 + hi * 4) =
              *(const u64*)&obv;
        }
    }
  }
  __threadfence();
  grid.sync();

  // ================= Phase D: output GEMM (256 jobs) =================
  for (int job = blockIdx.x; job < 256; job += G) {
    __syncthreads();
    gemm_tile(a.joint, a.cdst[6], a.bo, a.out, 2, 1.0f,
              (job >> 3) * 128, (job & 7) * 128, smem);
  }
}

// ---------- launch ----------
extern "C" void kernel_launch(void* const* d_in, const int* in_sizes, int n_in,
                              void* d_out, int out_size, void* d_ws, size_t ws_size,
                              hipStream_t stream) {
  u16* w = (u16*)d_ws;

  MegaArgs ma;
  ma.csrc[0] = (const float*)d_in[0];   // q
  ma.csrc[1] = (const float*)d_in[1];   // k
  ma.csrc[2] = (const float*)d_in[2];   // v
  ma.csrc[3] = (const float*)d_in[4];   // Wq
  ma.csrc[4] = (const float*)d_in[6];   // Wk
  ma.csrc[5] = (const float*)d_in[8];   // Wv
  ma.csrc[6] = (const float*)d_in[10];  // Wo
  ma.mask = (const int*)d_in[3];
  ma.bq = (const float*)d_in[5];
  ma.bk = (const float*)d_in[7];
  ma.bv = (const float*)d_in[9];
  ma.bo = (const float*)d_in[11];

  ma.qp = w;                       // (B,H,S,Dh)
  ma.kp = w + 4194304;             // (B,H,S,Dh)
  ma.vt = w + 8388608;             // (B,H,Dh,S)
  ma.cdst[0] = w + 12582912;       // qb (joint aliases after attn)
  ma.cdst[1] = w + 16777216;       // kb
  ma.cdst[2] = w + 20971520;       // vb
  ma.cdst[3] = w + 25165824;       // Wqb
  ma.cdst[4] = w + 26214400;       // Wkb
  ma.cdst[5] = w + 27262976;       // Wvb
  ma.cdst[6] = w + 28311552;       // Wob
  ma.pm = (u64*)(w + 29360128);
  ma.joint = ma.cdst[0];
  ma.out = (float*)d_out;

  static int nblk = 0;
  if (nblk == 0) {
    int per_cu = 0;
    if (hipOccupancyMaxActiveBlocksPerMultiprocessor(&per_cu, mega_kernel,
                                                     512, 0) == hipSuccess &&
        per_cu >= 1) {
      nblk = per_cu * 256;
      if (nblk > 512) nblk = 512;
    } else {
      nblk = 256;   // conservative fallback, phases are grid-stride robust
    }
  }

  void* kargs[] = {(void*)&ma};
  hipLaunchCooperativeKernel((const void*)mega_kernel, dim3(nblk), dim3(512),
                             kargs, 0, stream);
}

// Round 11
// 263.382 us; speedup vs baseline: 2.3142x; 2.3142x over previous
//
#include <hip/hip_runtime.h>

typedef unsigned short u16;
typedef unsigned int u32;
typedef unsigned long long u64;
typedef float f32x4 __attribute__((ext_vector_type(4)));
typedef float f32x16 __attribute__((ext_vector_type(16)));
typedef __bf16 bf16x4 __attribute__((ext_vector_type(4)));
typedef __bf16 bf16x8 __attribute__((ext_vector_type(8)));
typedef u16 u16x8 __attribute__((ext_vector_type(8)));
typedef u32 u32x4 __attribute__((ext_vector_type(4)));

#define QSCALE 0.18033688011112042f   /* 0.125 * log2(e) */

// ---------- helpers ----------
__device__ __forceinline__ u16 f2bf(float f) {
  unsigned int u = __float_as_uint(f);
  u += 0x7fffu + ((u >> 16) & 1u);   // round-to-nearest-even
  return (u16)(u >> 16);
}

// async global->LDS, 16B per lane; HW dest = readfirstlane(l) + lane*16.
__device__ __forceinline__ void async16(const void* g, void* l) {
  __builtin_amdgcn_global_load_lds(
      (__attribute__((address_space(1))) void*)g,
      (__attribute__((address_space(3))) void*)l,
      16, 0, 0);
}

__device__ __forceinline__ f32x4 mfma16(bf16x8 a, bf16x8 b, f32x4 c) {
  return __builtin_amdgcn_mfma_f32_16x16x32_bf16(a, b, c, 0, 0, 0);
}

__device__ __forceinline__ f32x16 mfma32(bf16x8 a, bf16x8 b, f32x16 c) {
  return __builtin_amdgcn_mfma_f32_32x32x16_bf16(a, b, c, 0, 0, 0);
}

// pack two f32 -> dword of 2 bf16 (RNE)
__device__ __forceinline__ u32 cvtpk(float lo, float hi) {
  u32 r;
  asm("v_cvt_pk_bf16_f32 %0, %1, %2" : "=v"(r) : "v"(lo), "v"(hi));
  return r;
}

// a' = {a.lo32lanes, b.lo32lanes}; b' = {a.hi32lanes, b.hi32lanes}
__device__ __forceinline__ void pswap(u32& a, u32& b) {
  asm("v_permlane32_swap_b32 %0, %1" : "+v"(a), "+v"(b));
}

// ---------- f32 -> bf16 bulk convert (7 tensors) ----------
struct CvtArgs {
  const float* src[7];
  u16* dst[7];
};

__global__ __launch_bounds__(256) void cvt_kernel(CvtArgs a) {
  int z = blockIdx.z;
  int n = (z < 3) ? 4194304 : 1048576;
  int base = (blockIdx.x * 256 + threadIdx.x) * 8;
  if (base >= n) return;
  const float* s = a.src[z] + base;
  f32x4 x0 = *(const f32x4*)s;
  f32x4 x1 = *(const f32x4*)(s + 4);
  u16x8 pk;
  pk[0]=f2bf(x0[0]); pk[1]=f2bf(x0[1]); pk[2]=f2bf(x0[2]); pk[3]=f2bf(x0[3]);
  pk[4]=f2bf(x1[0]); pk[5]=f2bf(x1[1]); pk[6]=f2bf(x1[2]); pk[7]=f2bf(x1[3]);
  *(u16x8*)(a.dst[z] + base) = pk;
}

// ---------- mask packing: (B,1,S,S) int32 -> (B,S,S/64) uint64 ----------
__global__ __launch_bounds__(256) void pack_mask_kernel(
    const int* __restrict__ mask, u64* __restrict__ pm) {
  int idx = blockIdx.x * 256 + threadIdx.x;
  const int4* src = (const int4*)(mask + (size_t)idx * 64);
  u64 bits = 0ull;
#pragma unroll
  for (int j = 0; j < 16; ++j) {
    int4 v = src[j];
    if (v.x) bits |= 1ull << (4 * j + 0);
    if (v.y) bits |= 1ull << (4 * j + 1);
    if (v.z) bits |= 1ull << (4 * j + 2);
    if (v.w) bits |= 1ull << (4 * j + 3);
  }
  pm[idx] = bits;
}

// ---------- GEMM, BK=64, XOR-swizzled LDS (T2), 128x128 tile ----------
// mode 0: out (B,H,S,Dh)  mode 1: out (B,H,Dh,S) (operands pre-swapped by
// caller; bias by row)  mode 2: MxN f32
// LDS tiles [128 rows][8 slot16]; slot content pre-swizzled at the GLOBAL
// source (rule 21): LDS[row][c] = global[row][ (c ^ (row&7))*8 .. +8 ].
// Fragment reads XOR the same pattern -> 2-way banks (free). BK=64 halves
// the per-block barrier-drain count vs BK=32 (16 k-steps of 32 MFMA).
__device__ __forceinline__ void gemm_body(const u16* __restrict__ A,
                                          const u16* __restrict__ W,
                                          const float* __restrict__ bias,
                                          void* __restrict__ outraw, int mode,
                                          float oscale, int m0, int n0) {
  alignas(16) __shared__ u16 lA[128 * 64];
  alignas(16) __shared__ u16 lB[128 * 64];
  const int tid = threadIdx.x;
  const int lane = tid & 63, wv = tid >> 6;
  const int wm = wv >> 1, wn = wv & 1;
  const int l15 = lane & 15, quad = lane >> 4;
  const int xsw = l15 & 7;                 // row&7 for all fragment rows

  // staging geometry: 1024 slots of 16B per matrix, 4 per thread.
  int srow[4], scol[4];
#pragma unroll
  for (int t = 0; t < 4; ++t) {
    int slot = t * 256 + tid;
    srow[t] = slot >> 3;
    scol[t] = ((slot & 7) ^ (srow[t] & 7)) * 8;   // pre-swizzled source col
  }

  f32x4 acc[4][4] = {};

  for (int k0 = 0; k0 < 1024; k0 += 64) {
#pragma unroll
    for (int t = 0; t < 4; ++t) {
      int slot = t * 256 + tid;
      async16(A + (size_t)(m0 + srow[t]) * 1024 + k0 + scol[t],
              (char*)lA + slot * 16);
      async16(W + (size_t)(n0 + srow[t]) * 1024 + k0 + scol[t],
              (char*)lB + slot * 16);
    }
    __syncthreads();
#pragma unroll
    for (int ks = 0; ks < 2; ++ks) {
      bf16x8 af[4], bfr[4];
#pragma unroll
      for (int i = 0; i < 4; ++i) {
        int c = ((ks * 4 + quad) ^ xsw) * 8;
        af[i]  = *(const bf16x8*)(lA + (wm * 64 + i * 16 + l15) * 64 + c);
        bfr[i] = *(const bf16x8*)(lB + (wn * 64 + i * 16 + l15) * 64 + c);
      }
#pragma unroll
      for (int i = 0; i < 4; ++i)
#pragma unroll
        for (int j = 0; j < 4; ++j)
          acc[i][j] = mfma16(af[i], bfr[j], acc[i][j]);
    }
    __syncthreads();
  }

#pragma unroll
  for (int i = 0; i < 4; ++i) {
    int mbase = m0 + wm * 64 + i * 16 + quad * 4;
#pragma unroll
    for (int j = 0; j < 4; ++j) {
      int n = n0 + wn * 64 + j * 16 + l15;
      float bv = bias[n];   // modes 0/2: bias by column
#pragma unroll
      for (int r = 0; r < 4; ++r) {
        int m = mbase + r;
        if (mode == 0) {
          float val = (acc[i][j][r] + bv) * oscale;
          int b = m >> 11, s = m & 2047, h = n >> 6, dh = n & 63;
          ((u16*)outraw)[((((size_t)b * 16 + h) * 2048 + s) << 6) + dh] = f2bf(val);
        } else if (mode == 1) {
          // swapped gemm: m = feature row, n = b*2048+s; bias by ROW
          float val = acc[i][j][r] + bias[m];
          int h = m >> 6, dh = m & 63, b = n >> 11, s = n & 2047;
          ((u16*)outraw)[((((size_t)b * 16 + h) * 64 + dh) << 11) + s] = f2bf(val);
        } else {
          float val = acc[i][j][r] + bv;
          ((float*)outraw)[(size_t)m * 1024 + n] = val;
        }
      }
    }
  }
}

// XCD-affine tile map: linear bid%8 selects XCD (round-robin dispatch), so
// give XCD x the 4-m-tile band {4x..4x+3} x all 8 n-tiles: A-panel 1MB +
// W 2MB resident in its 4MB L2 (vs previous mapping where every XCD
// streamed the whole 8MB A).
__device__ __forceinline__ void tile_map(int t, int& mt, int& nt) {
  mt = (t & 7) * 4 + ((t >> 3) & 3);   // 0..31
  nt = t >> 5;                          // 0..7
}

__global__ __launch_bounds__(256) void gemm_qkv_kernel(
    const u16* __restrict__ qb, const u16* __restrict__ kb, const u16* __restrict__ vb,
    const u16* __restrict__ Wqb, const float* __restrict__ bq,
    const u16* __restrict__ Wkb, const float* __restrict__ bk,
    const u16* __restrict__ Wvb, const float* __restrict__ bv,
    u16* __restrict__ qp, u16* __restrict__ kp, u16* __restrict__ vt) {
  int mt, nt;
  tile_map(blockIdx.x, mt, nt);
  if (blockIdx.y == 0)
    gemm_body(qb, Wqb, bq, qp, 0, QSCALE, mt * 128, nt * 128);
  else if (blockIdx.y == 1)
    gemm_body(kb, Wkb, bk, kp, 0, 1.0f, mt * 128, nt * 128);
  else
    // V projection computed TRANSPOSED (A<->W swapped) -> coalesced store.
    // m-range = 1024 features (nt), n-range = 4096 rows (mt).
    gemm_body(Wvb, vb, bv, vt, 1, 1.0f, nt * 128, mt * 128);
}

__global__ __launch_bounds__(256) void gemm_o_kernel(
    const u16* __restrict__ joint, const u16* __restrict__ Wob,
    const float* __restrict__ bo, float* __restrict__ out) {
  int mt, nt;
  tile_map(blockIdx.x, mt, nt);
  gemm_body(joint, Wob, bo, out, 2, 1.0f, mt * 128, nt * 128);
}

// ---------- flash attention: 32x32 MFMA, in-reg P, KV-split, 8-wave ----------
// (unchanged from round 6/8: 59.9 us, occupancy 33%, MfmaUtil 23)
__global__ __launch_bounds__(512, 2) void attn_kernel(
    const u16* __restrict__ qp, const u16* __restrict__ kp,
    const u16* __restrict__ vt, const u64* __restrict__ pm,
    u16* __restrict__ joint) {
  // smem: [0,8K) kbuf0 | [8K,16K) kbuf1 | [16K,24K) vbuf0 | [24K,32K) vbuf1
  // reused after the K-loop as float exch[4][64][17] (17.4 KB)
  alignas(16) __shared__ char smem[32768];

  const int tid = threadIdx.x, lane = tid & 63, wv = tid >> 6;
  const int l31 = lane & 31, hi = lane >> 5, l7 = lane & 7;
  const int qg = wv >> 1, kh = wv & 1;    // q-group (0..3), kv-half

  // XCD-bijective decode: xcd = bid&7 = grp>>2 (4 heads per XCD)
  const int bid = blockIdx.x;
  const int grp = ((bid & 7) << 2) | ((bid >> 3) & 3);   // 0..31 = (b,h)
  const int q0 = (bid >> 5) * 128;
  const int hd = grp & 15, b = grp >> 4;

  const size_t head_off = ((size_t)b * 16 + hd) * 2048 * 64;
  const u16* Qh = qp + head_off;   // [2048][64]  (pre-scaled)
  const u16* Kh = kp + head_off;   // [2048][64]
  const u16* Vh = vt + head_off;   // [64][2048]  (dh-major)
  const int qr = q0 + qg * 32 + l31;                    // this lane's q row
  const u32* pmq32 = (const u32*)(pm + ((size_t)b * 2048 + qr) * 32) + kh;

  // Q fragments: B-operand per dh-subtile d: lane holds Q[qr][d*16+hi*8+j]
  bf16x8 qf[4];
  {
    const u16* qrow = Qh + (size_t)qr * 64 + hi * 8;
#pragma unroll
    for (int d = 0; d < 4; ++d) qf[d] = *(const bf16x8*)(qrow + d * 16);
  }

  // staging: 512 slots of 16B per tile, ONE K-slot + ONE V-slot per thread.
  // slot sd -> row sd>>3, slot16 sd&7; source column pre-swizzled.
  const int sd = tid;
  const int kr = sd >> 3, ks = ((sd & 7) ^ (kr & 7)) * 8;
  const u16* kg = Kh + (size_t)kr * 64 + ks;
  const u16* vg = Vh + (size_t)kr * 2048 + ks;

  f32x16 O[2] = {};                // O^T: dh=g*32+(r&3)+8*(r>>2)+4*hi, q=l31
  f32x4 lacc = {};                 // 4-chain l partials (kv-half only)
  const f32x16 fz16 = {};

  // prologue: stage tile 0
  async16(kg, smem + sd * 16);
  async16(vg, smem + 16384 + sd * 16);

  for (int kt = 0; kt < 32; ++kt) {
    __syncthreads();

    // prefetch next tile
    if (kt != 31) {
      const size_t kadv = (size_t)(kt + 1) * 4096;   // 64 rows x 64 elems
      const int vadv = (kt + 1) * 64;                // +64 kv columns
      char* kd = smem + (((kt + 1) & 1) << 13);
      char* vd = smem + 16384 + (((kt + 1) & 1) << 13);
      async16(kg + kadv, kd + sd * 16);
      async16(vg + vadv, vd + sd * 16);
    }

    u32 wh = pmq32[2 * kt];        // mask bits for this wave's kv half
    const char* kc = smem + ((kt & 1) << 13);
    const char* vc = smem + 16384 + ((kt & 1) << 13);

    // ---- K fragments: A-operand, lane = K[kh*32+l31][d*16+hi*8+j] ----
    bf16x8 kf[4];
#pragma unroll
    for (int d = 0; d < 4; ++d)
      kf[d] = *(const bf16x8*)(kc + (kh * 32 + l31) * 128 +
                               (((2 * d + hi) ^ l7) << 4));

    // ---- S^T (this wave's 32x32 kv-half), chained over dh ----
    f32x16 S;
    {
      __builtin_amdgcn_s_setprio(1);
      f32x16 s = mfma32(kf[0], qf[0], fz16);
      s = mfma32(kf[1], qf[1], s);
      s = mfma32(kf[2], qf[2], s);
      S = mfma32(kf[3], qf[3], s);
      __builtin_amdgcn_s_setprio(0);
    }

    // ---- V fragments: A-operand, lane = V^T[g*32+l31][vks*16+hi*8+j] ----
    bf16x8 vf[2][2];
#pragma unroll
    for (int g = 0; g < 2; ++g)
#pragma unroll
      for (int t = 0; t < 2; ++t) {
        int vks = kh * 2 + t;
        vf[g][t] = *(const bf16x8*)(vc + (g * 32 + l31) * 128 +
                                    (((2 * vks + hi) ^ l7) << 4));
      }

    // ---- masked exp2 + l accumulation (kv' = (r&3)+8*(r>>2)+4*hi) ----
    {
      const int hi4 = hi * 4;
#pragma unroll
      for (int rq = 0; rq < 4; ++rq) {
        u32 nib = wh >> (rq * 8 + hi4);
#pragma unroll
        for (int r4 = 0; r4 < 4; ++r4) {
          int i = rq * 4 + r4;
          float pe = __builtin_amdgcn_exp2f(S[i]);
          S[i] = ((nib >> r4) & 1u) ? pe : 0.f;
        }
        f32x4 sv = {S[rq * 4 + 0], S[rq * 4 + 1], S[rq * 4 + 2], S[rq * 4 + 3]};
        lacc += sv;
      }
    }

    // ---- P^T -> PV B-operand, in-register (cvt_pk + permlane, T12) ----
    bf16x8 pf[2];
#pragma unroll
    for (int t = 0; t < 2; ++t) {
      int ra = t * 8;
      u32 w0a = cvtpk(S[ra + 0], S[ra + 1]);
      u32 w1a = cvtpk(S[ra + 2], S[ra + 3]);
      u32 w0b = cvtpk(S[ra + 4], S[ra + 5]);
      u32 w1b = cvtpk(S[ra + 6], S[ra + 7]);
      pswap(w0a, w0b);   // dword0 / dword2
      pswap(w1a, w1b);   // dword1 / dword3
      u32x4 tt = {w0a, w1a, w0b, w1b};
      pf[t] = __builtin_bit_cast(bf16x8, tt);
    }

    // ---- O^T += V^T . P^T (this kv-half's contribution) ----
    __builtin_amdgcn_s_setprio(1);
#pragma unroll
    for (int g = 0; g < 2; ++g) {
      f32x16 o = O[g];
      o = mfma32(vf[g][0], pf[0], o);
      O[g] = mfma32(vf[g][1], pf[1], o);
    }
    __builtin_amdgcn_s_setprio(0);
  }

  // ---- epilogue: cross-wave (kv-half) reduction via 2-round exchange ----
  float lp = (lacc[0] + lacc[1]) + (lacc[2] + lacc[3]);
  lp += __shfl_xor(lp, 32, 64);    // hi/lo lanes hold complementary kv rows
  __syncthreads();                 // all K/V tile reads done; smem reusable
  float* exch = (float*)smem;      // [4][64][17] floats, 17.4 KB
  float* e = exch + (qg * 64 + lane) * 17;
  if (kh == 1) {
#pragma unroll
    for (int i = 0; i < 16; ++i) e[i] = O[0][i];
    e[16] = lp;
  }
  __syncthreads();
  if (kh == 0) {
#pragma unroll
    for (int i = 0; i < 16; ++i) O[0][i] += e[i];
    lp += e[16];
  }
  __syncthreads();
  if (kh == 1) {
#pragma unroll
    for (int i = 0; i < 16; ++i) e[i] = O[1][i];
  }
  __syncthreads();
  if (kh == 0) {
#pragma unroll
    for (int i = 0; i < 16; ++i) O[1][i] += e[i];
    float inv = 1.0f / lp;
    size_t row_off = ((size_t)b * 2048 + qr) * 1024 + hd * 64;
#pragma unroll
    for (int g = 0; g < 2; ++g)
#pragma unroll
      for (int rq = 0; rq < 4; ++rq) {
        f32x4 ov = {O[g][rq * 4 + 0] * inv, O[g][rq * 4 + 1] * inv,
                    O[g][rq * 4 + 2] * inv, O[g][rq * 4 + 3] * inv};
        bf16x4 obv = __builtin_convertvector(ov, bf16x4);
        *(u64*)(joint + row_off + g * 32 + rq * 8 + hi * 4) =
            *(const u64*)&obv;
      }
  }
}

// ---------- launch ----------
extern "C" void kernel_launch(void* const* d_in, const int* in_sizes, int n_in,
                              void* d_out, int out_size, void* d_ws, size_t ws_size,
                              hipStream_t stream) {
  const float* q  = (const float*)d_in[0];
  const float* k  = (const float*)d_in[1];
  const float* v  = (const float*)d_in[2];
  const int* mask = (const int*)d_in[3];
  const float* Wq = (const float*)d_in[4];
  const float* bq = (const float*)d_in[5];
  const float* Wk = (const float*)d_in[6];
  const float* bk = (const float*)d_in[7];
  const float* Wv = (const float*)d_in[8];
  const float* bv = (const float*)d_in[9];
  const float* Wo = (const float*)d_in[10];
  const float* bo = (const float*)d_in[11];
  float* out = (float*)d_out;

  u16* w = (u16*)d_ws;
  u16* qp    = w;                         // (B,H,S,Dh)
  u16* kp    = w + 4194304;               // (B,H,S,Dh)
  u16* vt    = w + 8388608;               // (B,H,Dh,S)
  u16* qb    = w + 12582912;              // bf16 q; joint aliases after attn
  u16* kb    = w + 16777216;
  u16* vb    = w + 20971520;
  u16* Wqb   = w + 25165824;
  u16* Wkb   = w + 26214400;
  u16* Wvb   = w + 27262976;
  u16* Wob   = w + 28311552;
  u64* pm    = (u64*)(w + 29360128);
  u16* joint = qb;

  CvtArgs ca;
  ca.src[0] = q;  ca.dst[0] = qb;
  ca.src[1] = k;  ca.dst[1] = kb;
  ca.src[2] = v;  ca.dst[2] = vb;
  ca.src[3] = Wq; ca.dst[3] = Wqb;
  ca.src[4] = Wk; ca.dst[4] = Wkb;
  ca.src[5] = Wv; ca.dst[5] = Wvb;
  ca.src[6] = Wo; ca.dst[6] = Wob;

  pack_mask_kernel<<<dim3(512), dim3(256), 0, stream>>>(mask, pm);
  cvt_kernel<<<dim3(2048, 1, 7), dim3(256), 0, stream>>>(ca);
  gemm_qkv_kernel<<<dim3(256, 3), dim3(256), 0, stream>>>(
      qb, kb, vb, Wqb, bq, Wkb, bk, Wvb, bv, qp, kp, vt);
  attn_kernel<<<dim3(512), dim3(512), 0, stream>>>(qp, kp, vt, pm, joint);
  gemm_o_kernel<<<dim3(256), dim3(256), 0, stream>>>(joint, Wob, bo, out);
}